// Round 1
// baseline (390.692 us; speedup 1.0000x reference)
//
#include <hip/hip_runtime.h>
#include <math.h>

#define NUM_LOD 8

struct GridParams {
    const float* cb[NUM_LOD];
    int res[NUM_LOD];
};

// One thread per point. Params struct is wave-uniform -> res/cb live in SGPRs.
__global__ __launch_bounds__(256) void densegrid_kernel(
    const float2* __restrict__ pts, GridParams p, float* __restrict__ out, int n)
{
    int i = blockIdx.x * blockDim.x + threadIdx.x;
    if (i >= n) return;

    const float2 pt = pts[i];   // coalesced 8 B/lane

    float o[2 * NUM_LOD];
#pragma unroll
    for (int L = 0; L < NUM_LOD; ++L) {
        const int   res = p.res[L];
        const float s   = (float)(res - 1);
        // pts in [0,1): product in [0, res-1), floor stays in-bounds (matches ref: no clamp)
        const int ix = (int)floorf(pt.x * s);
        const int iy = (int)floorf(pt.y * s);
        const float2 f = ((const float2*)p.cb[L])[ix + iy * res];  // L2-resident gather
        o[L]           = f.x;   // out[n, 0*8 + L]
        o[NUM_LOD + L] = f.y;   // out[n, 1*8 + L]
    }

    // 64 B contiguous store per point, 4x float4
    float4* o4 = (float4*)(out + (size_t)i * (2 * NUM_LOD));
    o4[0] = make_float4(o[0],  o[1],  o[2],  o[3]);
    o4[1] = make_float4(o[4],  o[5],  o[6],  o[7]);
    o4[2] = make_float4(o[8],  o[9],  o[10], o[11]);
    o4[3] = make_float4(o[12], o[13], o[14], o[15]);
}

extern "C" void kernel_launch(void* const* d_in, const int* in_sizes, int n_in,
                              void* d_out, int out_size, void* d_ws, size_t ws_size,
                              hipStream_t stream)
{
    const float2* pts = (const float2*)d_in[0];
    const int n = in_sizes[0] / 2;

    GridParams p;
    for (int L = 0; L < NUM_LOD; ++L) {
        p.cb[L] = (const float*)d_in[L + 1];
        // in_sizes[L+1] == res*res*FEAT_DIM; derive res exactly from the size
        // (avoids replicating Python's float LOD truncation).
        const int cells = in_sizes[L + 1] / 2;
        p.res[L] = (int)(sqrt((double)cells) + 0.5);
    }

    const int block = 256;
    const int grid  = (n + block - 1) / block;
    densegrid_kernel<<<grid, block, 0, stream>>>(pts, p, (float*)d_out, n);
}

// Round 2
// 351.253 us; speedup vs baseline: 1.1123x; 1.1123x over previous
//
#include <hip/hip_runtime.h>
#include <math.h>

#define NUM_LOD 8
#define NLDS 3            // LODs 0..2 (16^2, 23^2, 35^2 cells = 16080 B) live in LDS
#define BLOCK 512
#define TPAD 17           // transpose-buffer stride in floats (odd -> conflict-free)

struct GridParams {
    const float* cb[NUM_LOD];
    int res[NUM_LOD];
    int ldsOff[NLDS];     // float offsets of each LDS codebook
    int ldsCnt[NLDS];     // float counts
};

__global__ __launch_bounds__(BLOCK) void densegrid_kernel(
    const float2* __restrict__ pts, GridParams p, float4* __restrict__ out4, long long n)
{
    __shared__ float cbLds[4096];          // >= 16080/4 = 4020 floats
    __shared__ float tbuf[BLOCK * TPAD];   // 34816 B transpose buffer

    const int t = threadIdx.x;

    // Phase A: stage small codebooks into LDS (coalesced float2 stream)
    for (int L = 0; L < NLDS; ++L) {
        const float2* src = (const float2*)p.cb[L];
        float2* dst = (float2*)&cbLds[p.ldsOff[L]];   // offsets are even -> 8B aligned
        const int cnt2 = p.ldsCnt[L] >> 1;
        for (int j = t; j < cnt2; j += BLOCK) dst[j] = src[j];
    }
    __syncthreads();

    // Phase B: one point per thread -> 16 floats into the transpose buffer
    const long long i = (long long)blockIdx.x * BLOCK + t;
    if (i < n) {
        const float2 pt = pts[i];          // coalesced 8 B/lane
        float o[16];
#pragma unroll
        for (int L = 0; L < NUM_LOD; ++L) {
            const int   res = p.res[L];
            const float s   = (float)(res - 1);
            const int ix = (int)floorf(pt.x * s);
            const int iy = (int)floorf(pt.y * s);
            const int idx = ix + iy * res;
            float2 f;
            if (L < NLDS) {                 // compile-time split (L is constant)
                f = ((const float2*)&cbLds[p.ldsOff[L]])[idx];   // LDS gather
            } else {
                f = ((const float2*)p.cb[L])[idx];               // L2 gather
            }
            o[L]     = f.x;                 // out[n, 0*8 + L]
            o[8 + L] = f.y;                 // out[n, 1*8 + L]
        }
#pragma unroll
        for (int j = 0; j < 16; ++j) tbuf[t * TPAD + j] = o[j];  // stride 17: no conflicts
    }
    __syncthreads();

    // Phase C: block-coalesced float4 stores (lane-consecutive -> 16 lines/instr)
    const long long base4 = (long long)blockIdx.x * (BLOCK * 4);
    const long long lim4  = n * 4;
#pragma unroll
    for (int k = 0; k < 4; ++k) {
        const int m = k * BLOCK + t;        // float4 index within block's output
        const long long g = base4 + m;
        if (g < lim4) {
            const int pnt = m >> 2, q = m & 3;
            const float* src = &tbuf[pnt * TPAD + q * 4];
            out4[g] = make_float4(src[0], src[1], src[2], src[3]);
        }
    }
}

extern "C" void kernel_launch(void* const* d_in, const int* in_sizes, int n_in,
                              void* d_out, int out_size, void* d_ws, size_t ws_size,
                              hipStream_t stream)
{
    const float2* pts = (const float2*)d_in[0];
    const long long n = in_sizes[0] / 2;

    GridParams p;
    int off = 0;
    for (int L = 0; L < NUM_LOD; ++L) {
        p.cb[L] = (const float*)d_in[L + 1];
        const int cells = in_sizes[L + 1] / 2;           // res*res
        p.res[L] = (int)(sqrt((double)cells) + 0.5);     // exact: derive res from size
        if (L < NLDS) {
            p.ldsOff[L] = off;
            p.ldsCnt[L] = in_sizes[L + 1];
            off += in_sizes[L + 1];
        }
    }

    const long long grid = (n + BLOCK - 1) / BLOCK;
    densegrid_kernel<<<(int)grid, BLOCK, 0, stream>>>(pts, p, (float4*)d_out, n);
}

// Round 3
// 341.456 us; speedup vs baseline: 1.1442x; 1.0287x over previous
//
#include <hip/hip_runtime.h>
#include <math.h>

#define NUM_LOD 8
#define NLDS 3            // LODs 0..2 (16^2, 23^2, 35^2 cells = 16080 B) live in LDS
#define BLOCK 512
#define PPT 2             // points per thread -> 10 outstanding L2 gathers/thread
#define TPAD 17           // transpose stride in floats (odd -> conflict-free)

struct GridParams {
    const float* cb[NUM_LOD];
    int res[NUM_LOD];
    int ldsOff[NLDS];
    int ldsCnt[NLDS];
};

__global__ __launch_bounds__(BLOCK) void densegrid_kernel(
    const float2* __restrict__ pts, GridParams p, float4* __restrict__ out4, long long n)
{
    __shared__ float cbLds[4096];          // 16080 B of small codebooks
    __shared__ float tbuf[BLOCK * TPAD];   // 34.8 KB transpose buffer (reused PPT times)

    const int t = threadIdx.x;

    // Phase A: stage small codebooks (coalesced float2 stream, L2 source)
    for (int L = 0; L < NLDS; ++L) {
        const float2* src = (const float2*)p.cb[L];
        float2* dst = (float2*)&cbLds[p.ldsOff[L]];
        const int cnt2 = p.ldsCnt[L] >> 1;
        for (int j = t; j < cnt2; j += BLOCK) dst[j] = src[j];
    }
    __syncthreads();

    // Phase B: PPT points per thread; all global gathers independent -> high MLP
    const long long base = (long long)blockIdx.x * (BLOCK * PPT);
    long long pi[PPT];
    float2 pt[PPT];
#pragma unroll
    for (int s = 0; s < PPT; ++s) {
        pi[s] = base + (long long)s * BLOCK + t;
        if (pi[s] < n) pt[s] = pts[pi[s]];     // coalesced
    }

    float o[PPT][16];
#pragma unroll
    for (int s = 0; s < PPT; ++s) {
        if (pi[s] >= n) continue;
#pragma unroll
        for (int L = 0; L < NUM_LOD; ++L) {
            const int   res = p.res[L];
            const float sc  = (float)(res - 1);
            const int ix = (int)floorf(pt[s].x * sc);
            const int iy = (int)floorf(pt[s].y * sc);
            const int idx = ix + iy * res;
            float2 f;
            if (L < NLDS) f = ((const float2*)&cbLds[p.ldsOff[L]])[idx];  // LDS gather
            else          f = ((const float2*)p.cb[L])[idx];              // L2 gather
            o[s][L]     = f.x;      // out[n, 0*8 + L]
            o[s][8 + L] = f.y;      // out[n, 1*8 + L]
        }
    }

    // Phase C: per point-chunk, LDS transpose then block-coalesced float4 stores
    const long long lim4 = n * 4;
#pragma unroll
    for (int s = 0; s < PPT; ++s) {
        if (s > 0) __syncthreads();            // protect tbuf reuse
        if (pi[s] < n) {
#pragma unroll
            for (int j = 0; j < 16; ++j) tbuf[t * TPAD + j] = o[s][j];
        }
        __syncthreads();
        const long long b4 = (base + (long long)s * BLOCK) * 4;
#pragma unroll
        for (int k = 0; k < 4; ++k) {
            const int m = k * BLOCK + t;       // float4 index within chunk
            const long long g = b4 + m;
            if (g < lim4) {
                const int pnt = m >> 2, q = m & 3;
                const float* src = &tbuf[pnt * TPAD + q * 4];
                out4[g] = make_float4(src[0], src[1], src[2], src[3]);
            }
        }
    }
}

extern "C" void kernel_launch(void* const* d_in, const int* in_sizes, int n_in,
                              void* d_out, int out_size, void* d_ws, size_t ws_size,
                              hipStream_t stream)
{
    const float2* pts = (const float2*)d_in[0];
    const long long n = in_sizes[0] / 2;

    GridParams p;
    int off = 0;
    for (int L = 0; L < NUM_LOD; ++L) {
        p.cb[L] = (const float*)d_in[L + 1];
        const int cells = in_sizes[L + 1] / 2;           // res*res
        p.res[L] = (int)(sqrt((double)cells) + 0.5);     // derive res exactly from size
        if (L < NLDS) {
            p.ldsOff[L] = off;
            p.ldsCnt[L] = in_sizes[L + 1];
            off += in_sizes[L + 1];
        }
    }

    const long long grid = (n + (long long)(BLOCK * PPT) - 1) / (BLOCK * PPT);
    densegrid_kernel<<<(int)grid, BLOCK, 0, stream>>>(pts, p, (float4*)d_out, n);
}